// Round 11
// baseline (282.054 us; speedup 1.0000x reference)
//
#include <hip/hip_runtime.h>
#include <math.h>

#define NLV 16
#define TBL (1u << 19)
#define HMASK (TBL - 1u)
#define PRIME1 2654435761u

#define BINSHIFT 7                   // 128 x 128 spatial bins
#define BINW (1 << BINSHIFT)
#define NBINS (BINW * BINW)
#define CAP 64                       // bucket slots per bin (= 1 wave)

struct Scales { float s[NLV]; };

__device__ __forceinline__ int point_bin(float2 p) {
    int bx = (int)(p.x * (float)BINW);
    int by = (int)(p.y * (float)BINW);
    return (by << BINSHIFT) + bx;
}

// ---- shared per-point body (exact R7 math: bitwise == reference) ----
__device__ __forceinline__ void process_point(
    int i, float2 p,
    const float2* __restrict__ table,
    const float*  __restrict__ W1,
    const float*  __restrict__ W2,
    float* __restrict__ out,
    const Scales& sc)
{
    float enc[32];
#pragma unroll
    for (int l = 0; l < NLV; ++l) {
        float s  = sc.s[l];
        float px = p.x * s;
        float py = p.y * s;
        float fpx = floorf(px), fpy = floorf(py);
        float fx = px - fpx, fy = py - fpy;
        unsigned bx = (unsigned)(int)fpx;
        unsigned by = (unsigned)(int)fpy;
        unsigned hy0 = by * PRIME1;
        unsigned hy1 = hy0 + PRIME1;     // (by+1)*PRIME1 mod 2^32
        const float2* tl = table + (size_t)l * TBL;
        float2 f00 = tl[( bx        ^ hy0) & HMASK];
        float2 f01 = tl[( bx        ^ hy1) & HMASK];
        float2 f10 = tl[((bx + 1u)  ^ hy0) & HMASK];
        float2 f11 = tl[((bx + 1u)  ^ hy1) & HMASK];
        float gx = 1.f - fx, gy = 1.f - fy;
        float w00 = gx * gy, w01 = gx * fy, w10 = fx * gy, w11 = fx * fy;
        enc[2*l]   = w00*f00.x + w01*f01.x + w10*f10.x + w11*f11.x;
        enc[2*l+1] = w00*f00.y + w01*f01.y + w10*f10.y + w11*f11.y;
    }

    float o0 = 0.f, o1 = 0.f, o2 = 0.f;
#pragma unroll
    for (int n = 0; n < 64; ++n) {
        float h = 0.f;
#pragma unroll
        for (int k = 0; k < 32; ++k)
            h = fmaf(enc[k], W1[n*32 + k], h);   // uniform addr -> s_load
        h = fmaxf(h, 0.f);
        o0 = fmaf(h, W2[      n], o0);
        o1 = fmaf(h, W2[ 64 + n], o1);
        o2 = fmaf(h, W2[128 + n], o2);
    }
    out[3*i + 0] = o0;
    out[3*i + 1] = o1;
    out[3*i + 2] = o2;
}

// ---- single prep pass: bucket up to CAP indices per bin, rest -> overflow ----
// Which points land in ovf is racy, but every point is processed exactly once
// with identical math -> out is deterministic.
__global__ void fill_kernel(const float2* __restrict__ pts, int* __restrict__ cnt,
                            int* __restrict__ bucket, int* __restrict__ ovf,
                            int* __restrict__ ovfcnt, int N) {
    int i = blockIdx.x * 256 + threadIdx.x;
    if (i >= N) return;
    int b = point_bin(pts[i]);
    int pos = atomicAdd(&cnt[b], 1);
    if (pos < CAP) bucket[b * CAP + pos] = i;
    else           ovf[atomicAdd(ovfcnt, 1)] = i;
}

// ---- main: 1 wave per bin (64 slots), 4 bins per 256-block ----
__global__ __launch_bounds__(256, 4) void hashgrid_mlp_bucket(
    const float2* __restrict__ pts,
    const float2* __restrict__ table,
    const int*    __restrict__ cnt,
    const int*    __restrict__ bucket,
    const float*  __restrict__ W1,
    const float*  __restrict__ W2,
    float* __restrict__ out, Scales sc)
{
    int bin  = blockIdx.x * 4 + (threadIdx.x >> 6);
    int slot = threadIdx.x & 63;
    int c = cnt[bin];
    if (c > CAP) c = CAP;
    if (slot >= c) return;
    int i = bucket[bin * CAP + slot];
    process_point(i, pts[i], table, W1, W2, out, sc);
}

// ---- overflow points (~5%): grid-stride, unsorted but exact ----
__global__ __launch_bounds__(256, 4) void hashgrid_mlp_ovf(
    const float2* __restrict__ pts,
    const float2* __restrict__ table,
    const int*    __restrict__ ovf,
    const int*    __restrict__ ovfcnt,
    const float*  __restrict__ W1,
    const float*  __restrict__ W2,
    float* __restrict__ out, Scales sc)
{
    int total = *ovfcnt;
    for (int t = blockIdx.x * 256 + threadIdx.x; t < total; t += 256 * 256) {
        int i = ovf[t];
        process_point(i, pts[i], table, W1, W2, out, sc);
    }
}

// ---- fallback (round-1) if ws too small ----
__global__ __launch_bounds__(256, 4) void hashgrid_mlp_fallback(
    const float2* __restrict__ pts, const float2* __restrict__ table,
    const float* __restrict__ W1, const float* __restrict__ W2,
    float* __restrict__ out, int N, Scales sc)
{
    int i = blockIdx.x * 256 + threadIdx.x;
    if (i >= N) return;
    process_point(i, pts[i], table, W1, W2, out, sc);
}

extern "C" void kernel_launch(void* const* d_in, const int* in_sizes, int n_in,
                              void* d_out, int out_size, void* d_ws, size_t ws_size,
                              hipStream_t stream) {
    const float2* pts   = (const float2*)d_in[0];
    const float2* table = (const float2*)d_in[1];
    const float*  W1    = (const float*)d_in[2];
    const float*  W2    = (const float*)d_in[3];
    float* out = (float*)d_out;
    int N = in_sizes[0] / 2;

    // Replicate numpy: np.floor(16 * 1.447269237440378 ** arange(16)).astype(f32)
    // (level 15 is a floor boundary: 4095, NOT 4096 — host pow matches numpy).
    Scales sc;
    for (int l = 0; l < NLV; ++l)
        sc.s[l] = (float)floor(16.0 * pow(1.447269237440378, (double)l));

    int blocks = (N + 255) / 256;
    size_t need = ((size_t)(NBINS + 1) + (size_t)NBINS * CAP + (size_t)N) * sizeof(int);

    if (ws_size >= need) {
        int* cnt    = (int*)d_ws;            // NBINS counters + [NBINS] = ovfcnt
        int* ovfcnt = cnt + NBINS;
        int* bucket = cnt + NBINS + 1;       // NBINS*CAP indices
        int* ovf    = bucket + (size_t)NBINS * CAP;  // up to N indices
        hipMemsetAsync(cnt, 0, (NBINS + 1) * sizeof(int), stream);
        hipLaunchKernelGGL(fill_kernel, dim3(blocks), dim3(256), 0, stream,
                           pts, cnt, bucket, ovf, ovfcnt, N);
        hipLaunchKernelGGL(hashgrid_mlp_bucket, dim3(NBINS / 4), dim3(256), 0, stream,
                           pts, table, cnt, bucket, W1, W2, out, sc);
        hipLaunchKernelGGL(hashgrid_mlp_ovf, dim3(256), dim3(256), 0, stream,
                           pts, table, ovf, ovfcnt, W1, W2, out, sc);
    } else {
        hipLaunchKernelGGL(hashgrid_mlp_fallback, dim3(blocks), dim3(256), 0, stream,
                           pts, table, W1, W2, out, N, sc);
    }
}

// Round 12
// 220.639 us; speedup vs baseline: 1.2783x; 1.2783x over previous
//
#include <hip/hip_runtime.h>
#include <math.h>

#define NLV 16
#define TBL (1u << 19)
#define HMASK (TBL - 1u)
#define PRIME1 2654435761u

#define BINSHIFT 7                   // 128 x 128 spatial bins
#define BINW (1 << BINSHIFT)
#define NBINS (BINW * BINW)

struct Scales { float s[NLV]; };

__device__ __forceinline__ int point_bin(float2 p) {
    int bx = (int)(p.x * (float)BINW);
    int by = (int)(p.y * (float)BINW);
    return (by << BINSHIFT) + bx;
}

// ---- pass 1: per-bin histogram, R replicas keyed by blockIdx%R ----
// (replica r lines stay XCD-local under round-robin dispatch)
__global__ void hist_kernel(const float2* __restrict__ pts, int* __restrict__ hist,
                            int N, int rmask) {
    int i = blockIdx.x * 256 + threadIdx.x;
    if (i >= N) return;
    int r = blockIdx.x & rmask;
    atomicAdd(&hist[r * NBINS + point_bin(pts[i])], 1);
}

// ---- pass 2 (FUSED binsum+scan+cursor, one single-block launch) ----
// Per 4096-int tile: acc = sum over R replica slices (coalesced int4),
// R9-verified shuffle scan of bin totals, then in-place rewrite of hist
// into bin-major cursors: cur[r][b] = binbase[b] + sum_{r'<r} hist[r'][b].
__global__ __launch_bounds__(1024) void scanfuse_kernel(int* __restrict__ hist, int R) {
    __shared__ int wsum[16];
    int tid = threadIdx.x;
    int lane = tid & 63, wid = tid >> 6;
    int carry = 0;
    int4* h4 = (int4*)hist;                 // per-replica slice = NBINS/4 int4s
    const int rstride = NBINS / 4;
    const int tiles = NBINS / 4096;         // 4
    for (int t = 0; t < tiles; ++t) {
        int idx = (t << 10) + tid;
        int4 acc = make_int4(0, 0, 0, 0);
        for (int r = 0; r < R; ++r) {
            int4 v = h4[r * rstride + idx];
            acc.x += v.x; acc.y += v.y; acc.z += v.z; acc.w += v.w;
        }
        int tsum = acc.x + acc.y + acc.z + acc.w;
        int x = tsum;
#pragma unroll
        for (int off = 1; off < 64; off <<= 1) {
            int y = __shfl_up(x, off, 64);
            if (lane >= off) x += y;
        }
        if (lane == 63) wsum[wid] = x;
        __syncthreads();
        if (wid == 0) {
            int s = (lane < 16) ? wsum[lane] : 0;
#pragma unroll
            for (int off = 1; off < 16; off <<= 1) {
                int y = __shfl_up(s, off, 64);
                if (lane >= off) s += y;
            }
            if (lane < 16) wsum[lane] = s;   // inclusive scan of wave sums
        }
        __syncthreads();
        int waveoff = (wid == 0) ? 0 : wsum[wid - 1];
        int base = carry + waveoff + (x - tsum);   // exclusive base, 1st of 4 bins
        // exclusive bases for this thread's 4 bins:
        int4 run;
        run.x = base;
        run.y = run.x + acc.x;
        run.z = run.y + acc.y;
        run.w = run.z + acc.z;
        // expand to replica cursors in place (bin-major, replica-minor):
        for (int r = 0; r < R; ++r) {
            int4 v = h4[r * rstride + idx];
            h4[r * rstride + idx] = run;
            run.x += v.x; run.y += v.y; run.z += v.z; run.w += v.w;
        }
        carry += wsum[15];
        __syncthreads();                     // wsum reused next tile
    }
}

// ---- pass 3: scatter indices via replicated cursors ----
__global__ void scatter_kernel(const float2* __restrict__ pts, int* __restrict__ cur,
                               int* __restrict__ sidx, int N, int rmask) {
    int i = blockIdx.x * 256 + threadIdx.x;
    if (i >= N) return;
    int r = blockIdx.x & rmask;
    int pos = atomicAdd(&cur[r * NBINS + point_bin(pts[i])], 1);
    sidx[pos] = i;
}

// ---- main kernel: exact R7/R10 structure (1 pt/thread, VGPR 36) ----
__global__ __launch_bounds__(256, 4) void hashgrid_mlp_kernel(
    const float2* __restrict__ pts,
    const float2* __restrict__ table,   // [16][524288] float2
    const int*    __restrict__ sidx,    // bin-sorted point indices
    const float*  __restrict__ W1,      // [64][32]
    const float*  __restrict__ W2,      // [3][64]
    float* __restrict__ out,            // [N][3]
    int N, Scales sc)
{
    int j = blockIdx.x * 256 + threadIdx.x;
    if (j >= N) return;
    int i = sidx[j];

    float2 p = pts[i];
    float enc[32];

#pragma unroll
    for (int l = 0; l < NLV; ++l) {
        float s  = sc.s[l];
        float px = p.x * s;              // f32 mul, bitwise == reference
        float py = p.y * s;
        float fpx = floorf(px), fpy = floorf(py);
        float fx = px - fpx, fy = py - fpy;
        unsigned bx = (unsigned)(int)fpx;
        unsigned by = (unsigned)(int)fpy;
        unsigned hy0 = by * PRIME1;
        unsigned hy1 = hy0 + PRIME1;     // (by+1)*PRIME1 mod 2^32
        const float2* tl = table + (size_t)l * TBL;
        float2 f00 = tl[( bx        ^ hy0) & HMASK];
        float2 f01 = tl[( bx        ^ hy1) & HMASK];
        float2 f10 = tl[((bx + 1u)  ^ hy0) & HMASK];
        float2 f11 = tl[((bx + 1u)  ^ hy1) & HMASK];
        float gx = 1.f - fx, gy = 1.f - fy;
        float w00 = gx * gy, w01 = gx * fy, w10 = fx * gy, w11 = fx * fy;
        enc[2*l]   = w00*f00.x + w01*f01.x + w10*f10.x + w11*f11.x;
        enc[2*l+1] = w00*f00.y + w01*f01.y + w10*f10.y + w11*f11.y;
    }

    float o0 = 0.f, o1 = 0.f, o2 = 0.f;
#pragma unroll
    for (int n = 0; n < 64; ++n) {
        float h = 0.f;
#pragma unroll
        for (int k = 0; k < 32; ++k)
            h = fmaf(enc[k], W1[n*32 + k], h);   // uniform addr -> s_load
        h = fmaxf(h, 0.f);
        o0 = fmaf(h, W2[      n], o0);
        o1 = fmaf(h, W2[ 64 + n], o1);
        o2 = fmaf(h, W2[128 + n], o2);
    }
    out[3*i + 0] = o0;
    out[3*i + 1] = o1;
    out[3*i + 2] = o2;
}

// ---- fallback (round-1) if ws too small for the sort ----
__global__ __launch_bounds__(256, 4) void hashgrid_mlp_fallback(
    const float2* __restrict__ pts, const float2* __restrict__ table,
    const float* __restrict__ W1, const float* __restrict__ W2,
    float* __restrict__ out, int N, Scales sc)
{
    int i = blockIdx.x * 256 + threadIdx.x;
    if (i >= N) return;
    float2 p = pts[i];
    float enc[32];
#pragma unroll
    for (int l = 0; l < NLV; ++l) {
        float s = sc.s[l];
        float px = p.x * s, py = p.y * s;
        float fpx = floorf(px), fpy = floorf(py);
        float fx = px - fpx, fy = py - fpy;
        unsigned bx = (unsigned)(int)fpx, by = (unsigned)(int)fpy;
        unsigned hy0 = by * PRIME1, hy1 = hy0 + PRIME1;
        const float2* tl = table + (size_t)l * TBL;
        float2 f00 = tl[( bx       ^ hy0) & HMASK];
        float2 f01 = tl[( bx       ^ hy1) & HMASK];
        float2 f10 = tl[((bx + 1u) ^ hy0) & HMASK];
        float2 f11 = tl[((bx + 1u) ^ hy1) & HMASK];
        float gx = 1.f - fx, gy = 1.f - fy;
        float w00 = gx * gy, w01 = gx * fy, w10 = fx * gy, w11 = fx * fy;
        enc[2*l]   = w00*f00.x + w01*f01.x + w10*f10.x + w11*f11.x;
        enc[2*l+1] = w00*f00.y + w01*f01.y + w10*f10.y + w11*f11.y;
    }
    float o0 = 0.f, o1 = 0.f, o2 = 0.f;
#pragma unroll
    for (int n = 0; n < 64; ++n) {
        float h = 0.f;
#pragma unroll
        for (int k = 0; k < 32; ++k) h = fmaf(enc[k], W1[n*32 + k], h);
        h = fmaxf(h, 0.f);
        o0 = fmaf(h, W2[n], o0); o1 = fmaf(h, W2[64 + n], o1); o2 = fmaf(h, W2[128 + n], o2);
    }
    out[3*i] = o0; out[3*i + 1] = o1; out[3*i + 2] = o2;
}

extern "C" void kernel_launch(void* const* d_in, const int* in_sizes, int n_in,
                              void* d_out, int out_size, void* d_ws, size_t ws_size,
                              hipStream_t stream) {
    const float2* pts   = (const float2*)d_in[0];
    const float2* table = (const float2*)d_in[1];
    const float*  W1    = (const float*)d_in[2];
    const float*  W2    = (const float*)d_in[3];
    float* out = (float*)d_out;
    int N = in_sizes[0] / 2;

    // Replicate numpy: np.floor(16 * 1.447269237440378 ** arange(16)).astype(f32)
    // (level 15 is a floor boundary: 4095, NOT 4096 — host pow matches numpy).
    Scales sc;
    for (int l = 0; l < NLV; ++l)
        sc.s[l] = (float)floor(16.0 * pow(1.447269237440378, (double)l));

    int blocks = (N + 255) / 256;
    int R = 8;                                        // replica count (pow2)
    size_t need = ((size_t)R * NBINS + N) * sizeof(int);
    if (ws_size < need) { R = 1; need = ((size_t)NBINS + N) * sizeof(int); }

    if (ws_size >= need) {
        int* hist = (int*)d_ws;          // R*NBINS counters -> cursors (in place)
        int* sidx = hist + R * NBINS;    // N sorted indices
        hipMemsetAsync(hist, 0, (size_t)R * NBINS * sizeof(int), stream);
        hipLaunchKernelGGL(hist_kernel,     dim3(blocks), dim3(256),  0, stream,
                           pts, hist, N, R - 1);
        hipLaunchKernelGGL(scanfuse_kernel, dim3(1),      dim3(1024), 0, stream,
                           hist, R);
        hipLaunchKernelGGL(scatter_kernel,  dim3(blocks), dim3(256),  0, stream,
                           pts, hist, sidx, N, R - 1);
        hipLaunchKernelGGL(hashgrid_mlp_kernel, dim3(blocks), dim3(256), 0, stream,
                           pts, table, sidx, W1, W2, out, N, sc);
    } else {
        hipLaunchKernelGGL(hashgrid_mlp_fallback, dim3(blocks), dim3(256), 0, stream,
                           pts, table, W1, W2, out, N, sc);
    }
}

// Round 13
// 217.872 us; speedup vs baseline: 1.2946x; 1.0127x over previous
//
#include <hip/hip_runtime.h>
#include <math.h>

#define NLV 16
#define TBL (1u << 19)
#define HMASK (TBL - 1u)
#define PRIME1 2654435761u

#define BINSHIFT 7                   // 128 x 128 spatial bins
#define BINW (1 << BINSHIFT)
#define NBINS (BINW * BINW)

struct Scales { float s[NLV]; };

typedef float vf2 __attribute__((ext_vector_type(2)));

// acc += a * w  (2x fp32 per issue; w is a wave-uniform SGPR pair -> VOP3P's
// one-scalar-source slot). hipcc never auto-emits v_pk_fma_f32 from scalar fmaf.
__device__ __forceinline__ void pk_fma(vf2& acc, vf2 a, vf2 w) {
    asm("v_pk_fma_f32 %0, %1, %2, %0" : "+v"(acc) : "v"(a), "s"(w));
}

__device__ __forceinline__ int point_bin(float2 p) {
    int bx = (int)(p.x * (float)BINW);
    int by = (int)(p.y * (float)BINW);
    return (by << BINSHIFT) + bx;
}

// ---- pass 1: per-bin histogram, R replicas keyed by blockIdx%R ----
__global__ void hist_kernel(const float2* __restrict__ pts, int* __restrict__ hist,
                            int N, int rmask) {
    int i = blockIdx.x * 256 + threadIdx.x;
    if (i >= N) return;
    int r = blockIdx.x & rmask;
    atomicAdd(&hist[r * NBINS + point_bin(pts[i])], 1);
}

// ---- pass 2 (fused binsum+scan+cursor, single block; verified R12) ----
__global__ __launch_bounds__(1024) void scanfuse_kernel(int* __restrict__ hist, int R) {
    __shared__ int wsum[16];
    int tid = threadIdx.x;
    int lane = tid & 63, wid = tid >> 6;
    int carry = 0;
    int4* h4 = (int4*)hist;
    const int rstride = NBINS / 4;
    const int tiles = NBINS / 4096;
    for (int t = 0; t < tiles; ++t) {
        int idx = (t << 10) + tid;
        int4 acc = make_int4(0, 0, 0, 0);
        for (int r = 0; r < R; ++r) {
            int4 v = h4[r * rstride + idx];
            acc.x += v.x; acc.y += v.y; acc.z += v.z; acc.w += v.w;
        }
        int tsum = acc.x + acc.y + acc.z + acc.w;
        int x = tsum;
#pragma unroll
        for (int off = 1; off < 64; off <<= 1) {
            int y = __shfl_up(x, off, 64);
            if (lane >= off) x += y;
        }
        if (lane == 63) wsum[wid] = x;
        __syncthreads();
        if (wid == 0) {
            int s = (lane < 16) ? wsum[lane] : 0;
#pragma unroll
            for (int off = 1; off < 16; off <<= 1) {
                int y = __shfl_up(s, off, 64);
                if (lane >= off) s += y;
            }
            if (lane < 16) wsum[lane] = s;
        }
        __syncthreads();
        int waveoff = (wid == 0) ? 0 : wsum[wid - 1];
        int base = carry + waveoff + (x - tsum);
        int4 run;
        run.x = base;
        run.y = run.x + acc.x;
        run.z = run.y + acc.y;
        run.w = run.z + acc.z;
        for (int r = 0; r < R; ++r) {
            int4 v = h4[r * rstride + idx];
            h4[r * rstride + idx] = run;
            run.x += v.x; run.y += v.y; run.z += v.z; run.w += v.w;
        }
        carry += wsum[15];
        __syncthreads();
    }
}

// ---- pass 3: scatter indices via replicated cursors ----
__global__ void scatter_kernel(const float2* __restrict__ pts, int* __restrict__ cur,
                               int* __restrict__ sidx, int N, int rmask) {
    int i = blockIdx.x * 256 + threadIdx.x;
    if (i >= N) return;
    int r = blockIdx.x & rmask;
    int pos = atomicAdd(&cur[r * NBINS + point_bin(pts[i])], 1);
    sidx[pos] = i;
}

// ---- main kernel: R7 gather structure + packed-fp32 MLP layer 1 ----
__global__ __launch_bounds__(256, 4) void hashgrid_mlp_kernel(
    const float2* __restrict__ pts,
    const float2* __restrict__ table,   // [16][524288] float2
    const int*    __restrict__ sidx,    // bin-sorted point indices
    const float*  __restrict__ W1,      // [64][32]
    const float*  __restrict__ W2,      // [3][64]
    float* __restrict__ out,            // [N][3]
    int N, Scales sc)
{
    int j = blockIdx.x * 256 + threadIdx.x;
    if (j >= N) return;
    int i = sidx[j];

    float2 p = pts[i];
    vf2 enc2[16];

#pragma unroll
    for (int l = 0; l < NLV; ++l) {
        float s  = sc.s[l];
        float px = p.x * s;              // f32 mul, bitwise == reference
        float py = p.y * s;
        float fpx = floorf(px), fpy = floorf(py);
        float fx = px - fpx, fy = py - fpy;
        unsigned bx = (unsigned)(int)fpx;
        unsigned by = (unsigned)(int)fpy;
        unsigned hy0 = by * PRIME1;
        unsigned hy1 = hy0 + PRIME1;     // (by+1)*PRIME1 mod 2^32
        const float2* tl = table + (size_t)l * TBL;
        float2 f00 = tl[( bx        ^ hy0) & HMASK];
        float2 f01 = tl[( bx        ^ hy1) & HMASK];
        float2 f10 = tl[((bx + 1u)  ^ hy0) & HMASK];
        float2 f11 = tl[((bx + 1u)  ^ hy1) & HMASK];
        float gx = 1.f - fx, gy = 1.f - fy;
        float w00 = gx * gy, w01 = gx * fy, w10 = fx * gy, w11 = fx * fy;
        float ex = w00*f00.x + w01*f01.x + w10*f10.x + w11*f11.x;
        float ey = w00*f00.y + w01*f01.y + w10*f10.y + w11*f11.y;
        enc2[l] = (vf2){ex, ey};
    }

    const vf2* w1v = (const vf2*)W1;     // uniform addr -> s_load_dwordx2 pairs
    float o0 = 0.f, o1 = 0.f, o2 = 0.f;
#pragma unroll
    for (int n = 0; n < 64; ++n) {
        vf2 hp0 = {0.f, 0.f}, hp1 = {0.f, 0.f};   // 2 chains: latency hiding
#pragma unroll
        for (int k = 0; k < 8; ++k) {
            pk_fma(hp0, enc2[2*k],     w1v[n*16 + 2*k]);
            pk_fma(hp1, enc2[2*k + 1], w1v[n*16 + 2*k + 1]);
        }
        float h = (hp0.x + hp0.y) + (hp1.x + hp1.y);
        h = fmaxf(h, 0.f);
        o0 = fmaf(h, W2[      n], o0);
        o1 = fmaf(h, W2[ 64 + n], o1);
        o2 = fmaf(h, W2[128 + n], o2);
    }
    out[3*i + 0] = o0;
    out[3*i + 1] = o1;
    out[3*i + 2] = o2;
}

// ---- fallback (round-1, scalar MLP) if ws too small for the sort ----
__global__ __launch_bounds__(256, 4) void hashgrid_mlp_fallback(
    const float2* __restrict__ pts, const float2* __restrict__ table,
    const float* __restrict__ W1, const float* __restrict__ W2,
    float* __restrict__ out, int N, Scales sc)
{
    int i = blockIdx.x * 256 + threadIdx.x;
    if (i >= N) return;
    float2 p = pts[i];
    float enc[32];
#pragma unroll
    for (int l = 0; l < NLV; ++l) {
        float s = sc.s[l];
        float px = p.x * s, py = p.y * s;
        float fpx = floorf(px), fpy = floorf(py);
        float fx = px - fpx, fy = py - fpy;
        unsigned bx = (unsigned)(int)fpx, by = (unsigned)(int)fpy;
        unsigned hy0 = by * PRIME1, hy1 = hy0 + PRIME1;
        const float2* tl = table + (size_t)l * TBL;
        float2 f00 = tl[( bx       ^ hy0) & HMASK];
        float2 f01 = tl[( bx       ^ hy1) & HMASK];
        float2 f10 = tl[((bx + 1u) ^ hy0) & HMASK];
        float2 f11 = tl[((bx + 1u) ^ hy1) & HMASK];
        float gx = 1.f - fx, gy = 1.f - fy;
        float w00 = gx * gy, w01 = gx * fy, w10 = fx * gy, w11 = fx * fy;
        enc[2*l]   = w00*f00.x + w01*f01.x + w10*f10.x + w11*f11.x;
        enc[2*l+1] = w00*f00.y + w01*f01.y + w10*f10.y + w11*f11.y;
    }
    float o0 = 0.f, o1 = 0.f, o2 = 0.f;
#pragma unroll
    for (int n = 0; n < 64; ++n) {
        float h = 0.f;
#pragma unroll
        for (int k = 0; k < 32; ++k) h = fmaf(enc[k], W1[n*32 + k], h);
        h = fmaxf(h, 0.f);
        o0 = fmaf(h, W2[n], o0); o1 = fmaf(h, W2[64 + n], o1); o2 = fmaf(h, W2[128 + n], o2);
    }
    out[3*i] = o0; out[3*i + 1] = o1; out[3*i + 2] = o2;
}

extern "C" void kernel_launch(void* const* d_in, const int* in_sizes, int n_in,
                              void* d_out, int out_size, void* d_ws, size_t ws_size,
                              hipStream_t stream) {
    const float2* pts   = (const float2*)d_in[0];
    const float2* table = (const float2*)d_in[1];
    const float*  W1    = (const float*)d_in[2];
    const float*  W2    = (const float*)d_in[3];
    float* out = (float*)d_out;
    int N = in_sizes[0] / 2;

    // Replicate numpy: np.floor(16 * 1.447269237440378 ** arange(16)).astype(f32)
    // (level 15 is a floor boundary: 4095, NOT 4096 — host pow matches numpy).
    Scales sc;
    for (int l = 0; l < NLV; ++l)
        sc.s[l] = (float)floor(16.0 * pow(1.447269237440378, (double)l));

    int blocks = (N + 255) / 256;
    int R = 8;                                        // replica count (pow2)
    size_t need = ((size_t)R * NBINS + N) * sizeof(int);
    if (ws_size < need) { R = 1; need = ((size_t)NBINS + N) * sizeof(int); }

    if (ws_size >= need) {
        int* hist = (int*)d_ws;          // R*NBINS counters -> cursors (in place)
        int* sidx = hist + R * NBINS;    // N sorted indices
        hipMemsetAsync(hist, 0, (size_t)R * NBINS * sizeof(int), stream);
        hipLaunchKernelGGL(hist_kernel,     dim3(blocks), dim3(256),  0, stream,
                           pts, hist, N, R - 1);
        hipLaunchKernelGGL(scanfuse_kernel, dim3(1),      dim3(1024), 0, stream,
                           hist, R);
        hipLaunchKernelGGL(scatter_kernel,  dim3(blocks), dim3(256),  0, stream,
                           pts, hist, sidx, N, R - 1);
        hipLaunchKernelGGL(hashgrid_mlp_kernel, dim3(blocks), dim3(256), 0, stream,
                           pts, table, sidx, W1, W2, out, N, sc);
    } else {
        hipLaunchKernelGGL(hashgrid_mlp_fallback, dim3(blocks), dim3(256), 0, stream,
                           pts, table, W1, W2, out, N, sc);
    }
}